// Round 1
// baseline (3079.962 us; speedup 1.0000x reference)
//
#include <hip/hip_runtime.h>

// GCN: N=100000 nodes, E=1600000 edges, F=H=128, D=64, O=1. All fp32.
// Pipeline:
//   deg -> dinv = rsqrt(deg+1)
//   h1 = relu(Agg(x@W1) + selfloop + b1)
//   h2 = relu(Agg(h1@Wh) + selfloop + bh)
//   y  = h2 @ (W2@Wo)   (layer-3 + output projection fused: scalar per node)
//   out = Agg_scalar(y) + selfloop + (b2@Wo + bo)

#define F_DIM 128

// ---- degree count (real edges only; +1 self-loop added in dinv) ----
__global__ void deg_kernel(const int* __restrict__ dst, float* __restrict__ deg, int E) {
    int e = blockIdx.x * blockDim.x + threadIdx.x;
    if (e < E) atomicAdd(&deg[dst[e]], 1.0f);
}

__global__ void dinv_kernel(float* __restrict__ d, int n) {
    int i = blockIdx.x * blockDim.x + threadIdx.x;
    if (i < n) d[i] = rsqrtf(d[i] + 1.0f);   // deg>=1 always (self loop)
}

// ---- w3 = W2 @ Wo  [128], c3 = b2.Wo + bo ----
__global__ void make_w3(const float* __restrict__ W2, const float* __restrict__ b2,
                        const float* __restrict__ Wo, const float* __restrict__ bo,
                        float* __restrict__ w3, float* __restrict__ c3) {
    int j = threadIdx.x;  // 128
    float s = 0.f;
    for (int d = 0; d < 64; ++d) s += W2[j * 64 + d] * Wo[d];
    w3[j] = s;
    if (j == 0) {
        float c = 0.f;
        for (int d = 0; d < 64; ++d) c += b2[d] * Wo[d];
        *c3 = c + bo[0];
    }
}

// ---- fp32 GEMM  C[n,128] = A[n,128] @ W[128,128], 8 rows/block ----
__global__ __launch_bounds__(128) void gemm128(const float* __restrict__ A,
                                               const float* __restrict__ W,
                                               float* __restrict__ C, int n) {
    __shared__ float Wl[64 * 128];   // one K-chunk of W
    __shared__ float Xl[8 * 128];    // 8 rows of A
    int j = threadIdx.x;             // output column
    int row0 = blockIdx.x * 8;

#pragma unroll
    for (int r = 0; r < 8; ++r) {
        int row = row0 + r;
        Xl[r * 128 + j] = (row < n) ? A[(size_t)row * 128 + j] : 0.0f;
    }

    float acc[8];
#pragma unroll
    for (int r = 0; r < 8; ++r) acc[r] = 0.f;

#pragma unroll
    for (int kc = 0; kc < 128; kc += 64) {
        __syncthreads();
        for (int i = 0; i < 64; ++i) Wl[i * 128 + j] = W[(size_t)(kc + i) * 128 + j];
        __syncthreads();
#pragma unroll 4
        for (int k = 0; k < 64; ++k) {
            float w = Wl[k * 128 + j];
#pragma unroll
            for (int r = 0; r < 8; ++r)
                acc[r] = fmaf(Xl[r * 128 + kc + k], w, acc[r]);
        }
    }

#pragma unroll
    for (int r = 0; r < 8; ++r) {
        int row = row0 + r;
        if (row < n) C[(size_t)row * 128 + j] = acc[r];
    }
}

// ---- edge aggregation, 128-wide rows: one wave per edge ----
__global__ __launch_bounds__(256) void agg128(const int* __restrict__ src,
                                              const int* __restrict__ dst,
                                              const float* __restrict__ dinv,
                                              const float* __restrict__ Hin,
                                              float* __restrict__ Hout, int E) {
    int wid = (int)((blockIdx.x * (size_t)blockDim.x + threadIdx.x) >> 6);
    int lane = threadIdx.x & 63;
    if (wid >= E) return;
    int s = src[wid], d = dst[wid];
    float nrm = dinv[s] * dinv[d];
    float2 v = *(const float2*)(Hin + (size_t)s * 128 + lane * 2);
    float* o = Hout + (size_t)d * 128 + lane * 2;
    atomicAdd(o, v.x * nrm);
    atomicAdd(o + 1, v.y * nrm);
}

// ---- scalar edge aggregation for fused layer 3 ----
__global__ void agg_scalar(const int* __restrict__ src, const int* __restrict__ dst,
                           const float* __restrict__ dinv, const float* __restrict__ y,
                           float* __restrict__ out, int E) {
    int e = blockIdx.x * blockDim.x + threadIdx.x;
    if (e < E) {
        int s = src[e], d = dst[e];
        atomicAdd(&out[d], y[s] * dinv[s] * dinv[d]);
    }
}

// ---- epilogue: agg += selfloop*gemm + bias, optional relu (in place) ----
__global__ void bias_selfloop(float* __restrict__ agg, const float* __restrict__ gout,
                              const float* __restrict__ dinv, const float* __restrict__ b,
                              int n, int do_relu) {
    int idx = blockIdx.x * blockDim.x + threadIdx.x;  // over n*32 float4s
    if (idx >= n * 32) return;
    int i = idx >> 5;
    int q = idx & 31;
    float di = dinv[i];
    float sl = di * di;
    float4 a = ((float4*)agg)[idx];
    float4 g = ((const float4*)gout)[idx];
    float4 bb = ((const float4*)b)[q];
    a.x += g.x * sl + bb.x;
    a.y += g.y * sl + bb.y;
    a.z += g.z * sl + bb.z;
    a.w += g.w * sl + bb.w;
    if (do_relu) {
        a.x = fmaxf(a.x, 0.f); a.y = fmaxf(a.y, 0.f);
        a.z = fmaxf(a.z, 0.f); a.w = fmaxf(a.w, 0.f);
    }
    ((float4*)agg)[idx] = a;
}

// ---- y[i] = dot(H[i,:], w3), one wave per row ----
__global__ __launch_bounds__(256) void dotw3(const float* __restrict__ H,
                                             const float* __restrict__ w3,
                                             float* __restrict__ y, int n) {
    int wid = (int)((blockIdx.x * (size_t)blockDim.x + threadIdx.x) >> 6);
    int lane = threadIdx.x & 63;
    if (wid >= n) return;
    float2 h = *(const float2*)(H + (size_t)wid * 128 + lane * 2);
    float2 w = *(const float2*)(w3 + lane * 2);
    float v = h.x * w.x + h.y * w.y;
#pragma unroll
    for (int off = 32; off > 0; off >>= 1) v += __shfl_down(v, off, 64);
    if (lane == 0) y[wid] = v;
}

__global__ void finalize(float* __restrict__ out, const float* __restrict__ y,
                         const float* __restrict__ dinv, const float* __restrict__ c3, int n) {
    int i = blockIdx.x * blockDim.x + threadIdx.x;
    if (i < n) {
        float di = dinv[i];
        out[i] += y[i] * di * di + c3[0];
    }
}

extern "C" void kernel_launch(void* const* d_in, const int* in_sizes, int n_in,
                              void* d_out, int out_size, void* d_ws, size_t ws_size,
                              hipStream_t stream) {
    const float* x  = (const float*)d_in[0];
    const int* ei   = (const int*)d_in[1];
    const float* W1 = (const float*)d_in[2];
    const float* b1 = (const float*)d_in[3];
    const float* Wh = (const float*)d_in[4];
    const float* bh = (const float*)d_in[5];
    const float* W2 = (const float*)d_in[6];
    const float* b2 = (const float*)d_in[7];
    const float* Wo = (const float*)d_in[8];
    const float* bo = (const float*)d_in[9];
    float* out = (float*)d_out;

    const int n = in_sizes[0] / F_DIM;
    const int E = in_sizes[1] / 2;
    const int* src = ei;
    const int* dst = ei + E;

    float* ws   = (float*)d_ws;
    float* dinv = ws;                    // [n]
    float* w3   = ws + n;                // [128]
    float* c3   = ws + n + 128;          // [1]
    float* bufA = ws + n + 256;          // [n*128]
    float* bufB = bufA + (size_t)n * 128;// [n*128]

    // degrees -> dinv
    hipMemsetAsync(dinv, 0, (size_t)n * 4, stream);
    deg_kernel<<<(E + 255) / 256, 256, 0, stream>>>(dst, dinv, E);
    dinv_kernel<<<(n + 255) / 256, 256, 0, stream>>>(dinv, n);
    make_w3<<<1, 128, 0, stream>>>(W2, b2, Wo, bo, w3, c3);

    // layer 1
    gemm128<<<(n + 7) / 8, 128, 0, stream>>>(x, W1, bufA, n);
    hipMemsetAsync(bufB, 0, (size_t)n * 128 * 4, stream);
    agg128<<<(E * 64 + 255) / 256, 256, 0, stream>>>(src, dst, dinv, bufA, bufB, E);
    bias_selfloop<<<(n * 32 + 255) / 256, 256, 0, stream>>>(bufB, bufA, dinv, b1, n, 1);

    // layer 2
    gemm128<<<(n + 7) / 8, 128, 0, stream>>>(bufB, Wh, bufA, n);
    hipMemsetAsync(bufB, 0, (size_t)n * 128 * 4, stream);
    agg128<<<(E * 64 + 255) / 256, 256, 0, stream>>>(src, dst, dinv, bufA, bufB, E);
    bias_selfloop<<<(n * 32 + 255) / 256, 256, 0, stream>>>(bufB, bufA, dinv, bh, n, 1);

    // layer 3 fused with output projection: y = h2 @ w3
    dotw3<<<((size_t)n * 64 + 255) / 256, 256, 0, stream>>>(bufB, w3, bufA, n);
    hipMemsetAsync(out, 0, (size_t)n * 4, stream);
    agg_scalar<<<(E + 255) / 256, 256, 0, stream>>>(src, dst, dinv, bufA, out, E);
    finalize<<<(n + 255) / 256, 256, 0, stream>>>(out, bufA, dinv, c3, n);
}

// Round 2
// 726.701 us; speedup vs baseline: 4.2383x; 4.2383x over previous
//
#include <hip/hip_runtime.h>

// GCN: N=100000, E=1600000, F=H=128, D=64, O=1. fp32.
// R2: CSR-ized aggregation (no float atomics).
//   CSR build: hist(int atomics) -> 3-kernel scan -> fill srcidx
//   g = dinv[row] * (h @ W)            (scale fused in GEMM epilogue)
//   h' = relu(dinv[d]*(sum_in g[s] + g[d]) + b)   (gather, fused epilogue)
//   layer3+proj fused: w3 = W2@Wo (vector), scalar gather.

#define F_DIM 128

// ---- CSR build ----
__global__ void hist_kernel(const int* __restrict__ dst, int* __restrict__ deg, int E) {
    int e = blockIdx.x * blockDim.x + threadIdx.x;
    if (e < E) atomicAdd(&deg[dst[e]], 1);
}

__global__ void scan_block(const int* __restrict__ deg, int* __restrict__ bsum, int n) {
    __shared__ int s[256];
    int i = blockIdx.x * 256 + threadIdx.x;
    s[threadIdx.x] = (i < n) ? deg[i] : 0;
    __syncthreads();
    for (int off = 128; off > 0; off >>= 1) {
        if (threadIdx.x < off) s[threadIdx.x] += s[threadIdx.x + off];
        __syncthreads();
    }
    if (threadIdx.x == 0) bsum[blockIdx.x] = s[0];
}

__global__ void scan_sums(const int* __restrict__ bsum, int* __restrict__ boff, int B) {
    __shared__ int s[512];
    int t = threadIdx.x;
    int v = (t < B) ? bsum[t] : 0;
    s[t] = v;
    __syncthreads();
    for (int off = 1; off < 512; off <<= 1) {
        int u = (t >= off) ? s[t - off] : 0;
        __syncthreads();
        s[t] += u;
        __syncthreads();
    }
    if (t < B) boff[t] = s[t] - v;   // exclusive
}

__global__ void scan_final(const int* __restrict__ deg, const int* __restrict__ boff,
                           int* __restrict__ rowptr, int* __restrict__ fill, int n) {
    __shared__ int s[256];
    int i = blockIdx.x * 256 + threadIdx.x;
    int v = (i < n) ? deg[i] : 0;
    s[threadIdx.x] = v;
    __syncthreads();
    for (int off = 1; off < 256; off <<= 1) {
        int u = (threadIdx.x >= off) ? s[threadIdx.x - off] : 0;
        __syncthreads();
        s[threadIdx.x] += u;
        __syncthreads();
    }
    if (i < n) {
        int excl = boff[blockIdx.x] + s[threadIdx.x] - v;
        rowptr[i] = excl;
        fill[i] = excl;
        if (i == n - 1) rowptr[n] = boff[blockIdx.x] + s[threadIdx.x];
    }
}

__global__ void fill_csr(const int* __restrict__ src, const int* __restrict__ dst,
                         int* __restrict__ fill, int* __restrict__ srcidx, int E) {
    int e = blockIdx.x * blockDim.x + threadIdx.x;
    if (e < E) {
        int pos = atomicAdd(&fill[dst[e]], 1);
        srcidx[pos] = src[e];
    }
}

__global__ void dinv_kernel(const int* __restrict__ deg, float* __restrict__ dinv, int n) {
    int i = blockIdx.x * blockDim.x + threadIdx.x;
    if (i < n) dinv[i] = rsqrtf((float)deg[i] + 1.0f);
}

// ---- w3 = W2 @ Wo  [128], c3 = b2.Wo + bo ----
__global__ void make_w3(const float* __restrict__ W2, const float* __restrict__ b2,
                        const float* __restrict__ Wo, const float* __restrict__ bo,
                        float* __restrict__ w3, float* __restrict__ c3) {
    int j = threadIdx.x;  // 128
    float s = 0.f;
    for (int d = 0; d < 64; ++d) s += W2[j * 64 + d] * Wo[d];
    w3[j] = s;
    if (j == 0) {
        float c = 0.f;
        for (int d = 0; d < 64; ++d) c += b2[d] * Wo[d];
        *c3 = c + bo[0];
    }
}

// ---- fp32 GEMM  C[n,128] = dinv[row] * (A[n,128] @ W[128,128]) ----
__global__ __launch_bounds__(128) void gemm128(const float* __restrict__ A,
                                               const float* __restrict__ W,
                                               const float* __restrict__ dinv,
                                               float* __restrict__ C, int n) {
    __shared__ float Wl[64 * 128];
    __shared__ float Xl[8 * 128];
    int j = threadIdx.x;
    int row0 = blockIdx.x * 8;

#pragma unroll
    for (int r = 0; r < 8; ++r) {
        int row = row0 + r;
        Xl[r * 128 + j] = (row < n) ? A[(size_t)row * 128 + j] : 0.0f;
    }

    float acc[8];
#pragma unroll
    for (int r = 0; r < 8; ++r) acc[r] = 0.f;

#pragma unroll
    for (int kc = 0; kc < 128; kc += 64) {
        __syncthreads();
        for (int i = 0; i < 64; ++i) Wl[i * 128 + j] = W[(size_t)(kc + i) * 128 + j];
        __syncthreads();
#pragma unroll 4
        for (int k = 0; k < 64; ++k) {
            float w = Wl[k * 128 + j];
#pragma unroll
            for (int r = 0; r < 8; ++r)
                acc[r] = fmaf(Xl[r * 128 + kc + k], w, acc[r]);
        }
    }

#pragma unroll
    for (int r = 0; r < 8; ++r) {
        int row = row0 + r;
        if (row < n) C[(size_t)row * 128 + j] = acc[r] * dinv[row];
    }
}

// ---- CSR gather aggregation, 128-wide: one wave per node ----
// out[d] = relu( dinv[d]*(sum_{s in in(d)} G[s] + G[d]) + b )
__global__ __launch_bounds__(256) void agg_csr128(const int* __restrict__ rowptr,
                                                  const int* __restrict__ srcidx,
                                                  const float* __restrict__ dinv,
                                                  const float* __restrict__ G,
                                                  const float* __restrict__ b,
                                                  float* __restrict__ out,
                                                  int n, int do_relu) {
    int wid = (int)((blockIdx.x * (size_t)blockDim.x + threadIdx.x) >> 6);
    int lane = threadIdx.x & 63;
    if (wid >= n) return;
    int beg = rowptr[wid], end = rowptr[wid + 1];

    float2 acc = *(const float2*)(G + (size_t)wid * 128 + lane * 2);  // self term
    int e = beg;
    for (; e + 3 < end; e += 4) {
        int s0 = srcidx[e], s1 = srcidx[e + 1], s2 = srcidx[e + 2], s3 = srcidx[e + 3];
        float2 v0 = *(const float2*)(G + (size_t)s0 * 128 + lane * 2);
        float2 v1 = *(const float2*)(G + (size_t)s1 * 128 + lane * 2);
        float2 v2 = *(const float2*)(G + (size_t)s2 * 128 + lane * 2);
        float2 v3 = *(const float2*)(G + (size_t)s3 * 128 + lane * 2);
        acc.x += v0.x + v1.x + v2.x + v3.x;
        acc.y += v0.y + v1.y + v2.y + v3.y;
    }
    for (; e < end; ++e) {
        int s = srcidx[e];
        float2 v = *(const float2*)(G + (size_t)s * 128 + lane * 2);
        acc.x += v.x;
        acc.y += v.y;
    }

    float di = dinv[wid];
    float2 bb = *(const float2*)(b + lane * 2);
    float ox = di * acc.x + bb.x;
    float oy = di * acc.y + bb.y;
    if (do_relu) { ox = fmaxf(ox, 0.f); oy = fmaxf(oy, 0.f); }
    *(float2*)(out + (size_t)wid * 128 + lane * 2) = make_float2(ox, oy);
}

// ---- ys[i] = dinv[i] * dot(H[i,:], w3), one wave per row ----
__global__ __launch_bounds__(256) void dotw3(const float* __restrict__ H,
                                             const float* __restrict__ w3,
                                             const float* __restrict__ dinv,
                                             float* __restrict__ ys, int n) {
    int wid = (int)((blockIdx.x * (size_t)blockDim.x + threadIdx.x) >> 6);
    int lane = threadIdx.x & 63;
    if (wid >= n) return;
    float2 h = *(const float2*)(H + (size_t)wid * 128 + lane * 2);
    float2 w = *(const float2*)(w3 + lane * 2);
    float v = h.x * w.x + h.y * w.y;
#pragma unroll
    for (int off = 32; off > 0; off >>= 1) v += __shfl_down(v, off, 64);
    if (lane == 0) ys[wid] = v * dinv[wid];
}

// ---- scalar CSR gather for fused layer3+proj ----
__global__ void agg_csr_scalar(const int* __restrict__ rowptr, const int* __restrict__ srcidx,
                               const float* __restrict__ dinv, const float* __restrict__ ys,
                               const float* __restrict__ c3, float* __restrict__ out, int n) {
    int i = blockIdx.x * blockDim.x + threadIdx.x;
    if (i >= n) return;
    int beg = rowptr[i], end = rowptr[i + 1];
    float acc = ys[i];
    int e = beg;
    for (; e + 3 < end; e += 4) {
        acc += ys[srcidx[e]] + ys[srcidx[e + 1]] + ys[srcidx[e + 2]] + ys[srcidx[e + 3]];
    }
    for (; e < end; ++e) acc += ys[srcidx[e]];
    out[i] = dinv[i] * acc + c3[0];
}

extern "C" void kernel_launch(void* const* d_in, const int* in_sizes, int n_in,
                              void* d_out, int out_size, void* d_ws, size_t ws_size,
                              hipStream_t stream) {
    const float* x  = (const float*)d_in[0];
    const int* ei   = (const int*)d_in[1];
    const float* W1 = (const float*)d_in[2];
    const float* b1 = (const float*)d_in[3];
    const float* Wh = (const float*)d_in[4];
    const float* bh = (const float*)d_in[5];
    const float* W2 = (const float*)d_in[6];
    const float* b2 = (const float*)d_in[7];
    const float* Wo = (const float*)d_in[8];
    const float* bo = (const float*)d_in[9];
    float* out = (float*)d_out;

    const int n = in_sizes[0] / F_DIM;
    const int E = in_sizes[1] / 2;
    const int* src = ei;
    const int* dst = ei + E;

    // workspace layout
    float* dinv = (float*)d_ws;                    // n
    float* w3   = dinv + n;                        // 128
    float* c3   = w3 + 128;                        // 1 (+127 pad)
    float* bufA = c3 + 128;                        // n*128
    float* bufB = bufA + (size_t)n * 128;          // n*128
    int*   deg  = (int*)(bufB + (size_t)n * 128);  // n
    int*   rowptr = deg + n;                       // n+1
    int*   fillc  = rowptr + n + 1;                // n
    int*   bsum   = fillc + n;                     // 1024
    int*   boff   = bsum + 1024;                   // 1024
    int*   srcidx = boff + 1024;                   // E

    const int B = (n + 255) / 256;

    // CSR build + dinv
    hipMemsetAsync(deg, 0, (size_t)n * 4, stream);
    hist_kernel<<<(E + 255) / 256, 256, 0, stream>>>(dst, deg, E);
    scan_block<<<B, 256, 0, stream>>>(deg, bsum, n);
    scan_sums<<<1, 512, 0, stream>>>(bsum, boff, B);
    scan_final<<<B, 256, 0, stream>>>(deg, boff, rowptr, fillc, n);
    fill_csr<<<(E + 255) / 256, 256, 0, stream>>>(src, dst, fillc, srcidx, E);
    dinv_kernel<<<B, 256, 0, stream>>>(deg, dinv, n);
    make_w3<<<1, 128, 0, stream>>>(W2, b2, Wo, bo, w3, c3);

    // layer 1
    gemm128<<<(n + 7) / 8, 128, 0, stream>>>(x, W1, dinv, bufA, n);
    agg_csr128<<<(int)(((size_t)n * 64 + 255) / 256), 256, 0, stream>>>(
        rowptr, srcidx, dinv, bufA, b1, bufB, n, 1);

    // layer 2
    gemm128<<<(n + 7) / 8, 128, 0, stream>>>(bufB, Wh, dinv, bufA, n);
    agg_csr128<<<(int)(((size_t)n * 64 + 255) / 256), 256, 0, stream>>>(
        rowptr, srcidx, dinv, bufA, bh, bufB, n, 1);

    // layer 3 + output projection
    dotw3<<<(int)(((size_t)n * 64 + 255) / 256), 256, 0, stream>>>(bufB, w3, dinv, bufA, n);
    agg_csr_scalar<<<B, 256, 0, stream>>>(rowptr, srcidx, dinv, bufA, c3, out, n);
}

// Round 3
// 572.757 us; speedup vs baseline: 5.3774x; 1.2688x over previous
//
#include <hip/hip_runtime.h>

// GCN: N=100000, E=1600000, F=H=128, D=64, O=1. fp32.
// R3: register-tiled fp32 GEMM (8x8/thread, BK=32 LDS staging) +
//     float4 2-edge-per-wave CSR gather. CSR build unchanged.

#define F_DIM 128

// ---- CSR build ----
__global__ void hist_kernel(const int* __restrict__ dst, int* __restrict__ deg, int E) {
    int e = blockIdx.x * blockDim.x + threadIdx.x;
    if (e < E) atomicAdd(&deg[dst[e]], 1);
}

__global__ void scan_block(const int* __restrict__ deg, int* __restrict__ bsum, int n) {
    __shared__ int s[256];
    int i = blockIdx.x * 256 + threadIdx.x;
    s[threadIdx.x] = (i < n) ? deg[i] : 0;
    __syncthreads();
    for (int off = 128; off > 0; off >>= 1) {
        if (threadIdx.x < off) s[threadIdx.x] += s[threadIdx.x + off];
        __syncthreads();
    }
    if (threadIdx.x == 0) bsum[blockIdx.x] = s[0];
}

__global__ void scan_sums(const int* __restrict__ bsum, int* __restrict__ boff, int B) {
    __shared__ int s[512];
    int t = threadIdx.x;
    int v = (t < B) ? bsum[t] : 0;
    s[t] = v;
    __syncthreads();
    for (int off = 1; off < 512; off <<= 1) {
        int u = (t >= off) ? s[t - off] : 0;
        __syncthreads();
        s[t] += u;
        __syncthreads();
    }
    if (t < B) boff[t] = s[t] - v;   // exclusive
}

__global__ void scan_final(const int* __restrict__ deg, const int* __restrict__ boff,
                           int* __restrict__ rowptr, int* __restrict__ fill, int n) {
    __shared__ int s[256];
    int i = blockIdx.x * 256 + threadIdx.x;
    int v = (i < n) ? deg[i] : 0;
    s[threadIdx.x] = v;
    __syncthreads();
    for (int off = 1; off < 256; off <<= 1) {
        int u = (threadIdx.x >= off) ? s[threadIdx.x - off] : 0;
        __syncthreads();
        s[threadIdx.x] += u;
        __syncthreads();
    }
    if (i < n) {
        int excl = boff[blockIdx.x] + s[threadIdx.x] - v;
        rowptr[i] = excl;
        fill[i] = excl;
        if (i == n - 1) rowptr[n] = boff[blockIdx.x] + s[threadIdx.x];
    }
}

__global__ void fill_csr(const int* __restrict__ src, const int* __restrict__ dst,
                         int* __restrict__ fill, int* __restrict__ srcidx, int E) {
    int e = blockIdx.x * blockDim.x + threadIdx.x;
    if (e < E) {
        int pos = atomicAdd(&fill[dst[e]], 1);
        srcidx[pos] = src[e];
    }
}

__global__ void dinv_kernel(const int* __restrict__ deg, float* __restrict__ dinv, int n) {
    int i = blockIdx.x * blockDim.x + threadIdx.x;
    if (i < n) dinv[i] = rsqrtf((float)deg[i] + 1.0f);
}

// ---- w3 = W2 @ Wo  [128], c3 = b2.Wo + bo ----
__global__ void make_w3(const float* __restrict__ W2, const float* __restrict__ b2,
                        const float* __restrict__ Wo, const float* __restrict__ bo,
                        float* __restrict__ w3, float* __restrict__ c3) {
    int j = threadIdx.x;  // 128
    float s = 0.f;
    for (int d = 0; d < 64; ++d) s += W2[j * 64 + d] * Wo[d];
    w3[j] = s;
    if (j == 0) {
        float c = 0.f;
        for (int d = 0; d < 64; ++d) c += b2[d] * Wo[d];
        *c3 = c + bo[0];
    }
}

// ---- fp32 GEMM  C[n,128] = dinv[row] * (A[n,128] @ W[128,128]) ----
// 256 threads, BM=128 rows/block, 8x8 outputs/thread (split 4+4, 64 apart).
#define BK 32
#define LDP 132   // padded row stride (floats), 528B = 16B-aligned
__global__ __launch_bounds__(256, 4) void gemm_rt(const float* __restrict__ A,
                                                  const float* __restrict__ W,
                                                  const float* __restrict__ dinv,
                                                  float* __restrict__ C, int n) {
    __shared__ float As[BK][LDP];  // As[k][r] = A[row0+r][kc+k]
    __shared__ float Ws[BK][LDP];  // Ws[k][c] = W[kc+k][c]
    const int tid = threadIdx.x;
    const int tx = tid & 15;       // col group
    const int ty = tid >> 4;       // row group
    const int row0 = blockIdx.x * 128;

    float acc[8][8];
#pragma unroll
    for (int i = 0; i < 8; ++i)
#pragma unroll
        for (int j = 0; j < 8; ++j) acc[i][j] = 0.f;

    for (int kc = 0; kc < 128; kc += BK) {
        // stage A tile transposed: 128 rows x 32 k
#pragma unroll
        for (int i = 0; i < 4; ++i) {
            int idx = tid + 256 * i;
            int r = idx >> 3, q = idx & 7;          // q: float4 within k-range
            int row = row0 + r;
            float4 v = (row < n) ? *(const float4*)(A + (size_t)row * 128 + kc + q * 4)
                                 : make_float4(0.f, 0.f, 0.f, 0.f);
            As[q * 4 + 0][r] = v.x;
            As[q * 4 + 1][r] = v.y;
            As[q * 4 + 2][r] = v.z;
            As[q * 4 + 3][r] = v.w;
        }
        // stage W tile: 32 k x 128 c
#pragma unroll
        for (int i = 0; i < 4; ++i) {
            int idx = tid + 256 * i;
            int k = idx >> 5, q = idx & 31;
            float4 v = *(const float4*)(W + (size_t)(kc + k) * 128 + q * 4);
            *(float4*)(&Ws[k][q * 4]) = v;
        }
        __syncthreads();

#pragma unroll 8
        for (int k = 0; k < BK; ++k) {
            float a[8], w[8];
            *(float4*)&a[0] = *(const float4*)(&As[k][ty * 4]);
            *(float4*)&a[4] = *(const float4*)(&As[k][64 + ty * 4]);
            *(float4*)&w[0] = *(const float4*)(&Ws[k][tx * 4]);
            *(float4*)&w[4] = *(const float4*)(&Ws[k][64 + tx * 4]);
#pragma unroll
            for (int i = 0; i < 8; ++i)
#pragma unroll
                for (int j = 0; j < 8; ++j)
                    acc[i][j] = fmaf(a[i], w[j], acc[i][j]);
        }
        __syncthreads();
    }

    // epilogue: rows = row0 + ty*4 + (i&3) + (i>=4)*64; cols = tx*4 + (j>=4)*64
#pragma unroll
    for (int i = 0; i < 8; ++i) {
        int row = row0 + ty * 4 + (i & 3) + ((i >= 4) ? 64 : 0);
        if (row < n) {
            float di = dinv[row];
            float4 o0, o1;
            o0.x = acc[i][0] * di; o0.y = acc[i][1] * di;
            o0.z = acc[i][2] * di; o0.w = acc[i][3] * di;
            o1.x = acc[i][4] * di; o1.y = acc[i][5] * di;
            o1.z = acc[i][6] * di; o1.w = acc[i][7] * di;
            *(float4*)(C + (size_t)row * 128 + tx * 4) = o0;
            *(float4*)(C + (size_t)row * 128 + 64 + tx * 4) = o1;
        }
    }
}

// ---- CSR gather aggregation: one wave per node, 2 edges in flight ----
// out[d] = relu( dinv[d]*(sum_{s in in(d)} G[s] + G[d]) + b )
__global__ __launch_bounds__(256) void agg_csr128(const int* __restrict__ rowptr,
                                                  const int* __restrict__ srcidx,
                                                  const float* __restrict__ dinv,
                                                  const float* __restrict__ G,
                                                  const float* __restrict__ b,
                                                  float* __restrict__ out,
                                                  int n, int do_relu) {
    int wid = (int)((blockIdx.x * (size_t)blockDim.x + threadIdx.x) >> 6);
    int lane = threadIdx.x & 63;
    if (wid >= n) return;
    int half = lane >> 5;   // 0/1: alternating edges
    int l = lane & 31;      // float4 slot within row

    int beg = rowptr[wid], end = rowptr[wid + 1];
    float4 acc = make_float4(0.f, 0.f, 0.f, 0.f);
    if (half == 0)  // self-loop term
        acc = *(const float4*)(G + (size_t)wid * 128 + l * 4);

    int e = beg + half;
    for (; e + 6 < end; e += 8) {
        int s0 = srcidx[e], s1 = srcidx[e + 2], s2 = srcidx[e + 4], s3 = srcidx[e + 6];
        float4 v0 = *(const float4*)(G + (size_t)s0 * 128 + l * 4);
        float4 v1 = *(const float4*)(G + (size_t)s1 * 128 + l * 4);
        float4 v2 = *(const float4*)(G + (size_t)s2 * 128 + l * 4);
        float4 v3 = *(const float4*)(G + (size_t)s3 * 128 + l * 4);
        acc.x += v0.x + v1.x + v2.x + v3.x;
        acc.y += v0.y + v1.y + v2.y + v3.y;
        acc.z += v0.z + v1.z + v2.z + v3.z;
        acc.w += v0.w + v1.w + v2.w + v3.w;
    }
    for (; e < end; e += 2) {
        int s = srcidx[e];
        float4 v = *(const float4*)(G + (size_t)s * 128 + l * 4);
        acc.x += v.x; acc.y += v.y; acc.z += v.z; acc.w += v.w;
    }

    // combine half-waves
    acc.x += __shfl_xor(acc.x, 32, 64);
    acc.y += __shfl_xor(acc.y, 32, 64);
    acc.z += __shfl_xor(acc.z, 32, 64);
    acc.w += __shfl_xor(acc.w, 32, 64);

    if (half == 0) {
        float di = dinv[wid];
        float4 bb = *(const float4*)(b + l * 4);
        float4 o;
        o.x = di * acc.x + bb.x;
        o.y = di * acc.y + bb.y;
        o.z = di * acc.z + bb.z;
        o.w = di * acc.w + bb.w;
        if (do_relu) {
            o.x = fmaxf(o.x, 0.f); o.y = fmaxf(o.y, 0.f);
            o.z = fmaxf(o.z, 0.f); o.w = fmaxf(o.w, 0.f);
        }
        *(float4*)(out + (size_t)wid * 128 + l * 4) = o;
    }
}

// ---- ys[i] = dinv[i] * dot(H[i,:], w3), one wave per row ----
__global__ __launch_bounds__(256) void dotw3(const float* __restrict__ H,
                                             const float* __restrict__ w3,
                                             const float* __restrict__ dinv,
                                             float* __restrict__ ys, int n) {
    int wid = (int)((blockIdx.x * (size_t)blockDim.x + threadIdx.x) >> 6);
    int lane = threadIdx.x & 63;
    if (wid >= n) return;
    float2 h = *(const float2*)(H + (size_t)wid * 128 + lane * 2);
    float2 w = *(const float2*)(w3 + lane * 2);
    float v = h.x * w.x + h.y * w.y;
#pragma unroll
    for (int off = 32; off > 0; off >>= 1) v += __shfl_down(v, off, 64);
    if (lane == 0) ys[wid] = v * dinv[wid];
}

// ---- scalar CSR gather for fused layer3+proj ----
__global__ void agg_csr_scalar(const int* __restrict__ rowptr, const int* __restrict__ srcidx,
                               const float* __restrict__ dinv, const float* __restrict__ ys,
                               const float* __restrict__ c3, float* __restrict__ out, int n) {
    int i = blockIdx.x * blockDim.x + threadIdx.x;
    if (i >= n) return;
    int beg = rowptr[i], end = rowptr[i + 1];
    float acc = ys[i];
    int e = beg;
    for (; e + 3 < end; e += 4) {
        acc += ys[srcidx[e]] + ys[srcidx[e + 1]] + ys[srcidx[e + 2]] + ys[srcidx[e + 3]];
    }
    for (; e < end; ++e) acc += ys[srcidx[e]];
    out[i] = dinv[i] * acc + c3[0];
}

extern "C" void kernel_launch(void* const* d_in, const int* in_sizes, int n_in,
                              void* d_out, int out_size, void* d_ws, size_t ws_size,
                              hipStream_t stream) {
    const float* x  = (const float*)d_in[0];
    const int* ei   = (const int*)d_in[1];
    const float* W1 = (const float*)d_in[2];
    const float* b1 = (const float*)d_in[3];
    const float* Wh = (const float*)d_in[4];
    const float* bh = (const float*)d_in[5];
    const float* W2 = (const float*)d_in[6];
    const float* b2 = (const float*)d_in[7];
    const float* Wo = (const float*)d_in[8];
    const float* bo = (const float*)d_in[9];
    float* out = (float*)d_out;

    const int n = in_sizes[0] / F_DIM;
    const int E = in_sizes[1] / 2;
    const int* src = ei;
    const int* dst = ei + E;

    // workspace layout
    float* dinv = (float*)d_ws;                    // n
    float* w3   = dinv + n;                        // 128
    float* c3   = w3 + 128;                        // 1 (+127 pad)
    float* bufA = c3 + 128;                        // n*128
    float* bufB = bufA + (size_t)n * 128;          // n*128
    int*   deg  = (int*)(bufB + (size_t)n * 128);  // n
    int*   rowptr = deg + n;                       // n+1
    int*   fillc  = rowptr + n + 1;                // n
    int*   bsum   = fillc + n;                     // 1024
    int*   boff   = bsum + 1024;                   // 1024
    int*   srcidx = boff + 1024;                   // E

    const int B = (n + 255) / 256;

    // CSR build + dinv
    hipMemsetAsync(deg, 0, (size_t)n * 4, stream);
    hist_kernel<<<(E + 255) / 256, 256, 0, stream>>>(dst, deg, E);
    scan_block<<<B, 256, 0, stream>>>(deg, bsum, n);
    scan_sums<<<1, 512, 0, stream>>>(bsum, boff, B);
    scan_final<<<B, 256, 0, stream>>>(deg, boff, rowptr, fillc, n);
    fill_csr<<<(E + 255) / 256, 256, 0, stream>>>(src, dst, fillc, srcidx, E);
    dinv_kernel<<<B, 256, 0, stream>>>(deg, dinv, n);
    make_w3<<<1, 128, 0, stream>>>(W2, b2, Wo, bo, w3, c3);

    const int GB = (n + 127) / 128;  // gemm blocks

    // layer 1
    gemm_rt<<<GB, 256, 0, stream>>>(x, W1, dinv, bufA, n);
    agg_csr128<<<(int)(((size_t)n * 64 + 255) / 256), 256, 0, stream>>>(
        rowptr, srcidx, dinv, bufA, b1, bufB, n, 1);

    // layer 2
    gemm_rt<<<GB, 256, 0, stream>>>(bufB, Wh, dinv, bufA, n);
    agg_csr128<<<(int)(((size_t)n * 64 + 255) / 256), 256, 0, stream>>>(
        rowptr, srcidx, dinv, bufA, bh, bufB, n, 1);

    // layer 3 + output projection
    dotw3<<<(int)(((size_t)n * 64 + 255) / 256), 256, 0, stream>>>(bufB, w3, dinv, bufA, n);
    agg_csr_scalar<<<B, 256, 0, stream>>>(rowptr, srcidx, dinv, bufA, c3, out, n);
}

// Round 4
// 518.812 us; speedup vs baseline: 5.9366x; 1.1040x over previous
//
#include <hip/hip_runtime.h>

// GCN: N=100000, E=1600000, F=H=128, D=64, O=1. fp32.
// R4: CSR build via 1-pass bucket sort (dst>>7, 782 buckets) + per-bucket
//     LDS compaction. Replaces random-scatter fill_csr (105MB writes) and
//     hist_kernel. Layers unchanged from R3.

#define F_DIM 128
#define CHUNK 8192
typedef unsigned long long u64;

// ---- bucket histogram: hist[bin*NB + blk] = #edges of chunk blk in bucket bin
__global__ __launch_bounds__(256) void histH(const int* __restrict__ dst, int* __restrict__ hist,
                                             int E, int NBKT, int NB) {
    __shared__ int bins[1024];
    int blk = blockIdx.x;
    for (int i = threadIdx.x; i < NBKT; i += 256) bins[i] = 0;
    __syncthreads();
    int beg = blk * CHUNK, end = min(E, beg + CHUNK);
    for (int e = beg + threadIdx.x; e < end; e += 256)
        atomicAdd(&bins[dst[e] >> 7], 1);
    __syncthreads();
    for (int i = threadIdx.x; i < NBKT; i += 256)
        hist[i * NB + blk] = bins[i];
}

// ---- per-bin totals ----
__global__ void scanK1(const int* __restrict__ hist, int* __restrict__ binsum,
                       int NBKT, int NB) {
    int bin = blockIdx.x * 256 + threadIdx.x;
    if (bin >= NBKT) return;
    int s = 0;
    for (int b = 0; b < NB; ++b) s += hist[bin * NB + b];
    binsum[bin] = s;
}

// ---- exclusive scan of bin totals -> bucket bases (NBKT <= 1024) ----
__global__ void scanK2(const int* __restrict__ binsum, int* __restrict__ binbase,
                       int NBKT, int E) {
    __shared__ int s[1024];
    int t = threadIdx.x;
    int v = (t < NBKT) ? binsum[t] : 0;
    s[t] = v;
    __syncthreads();
    for (int off = 1; off < 1024; off <<= 1) {
        int u = (t >= off) ? s[t - off] : 0;
        __syncthreads();
        s[t] += u;
        __syncthreads();
    }
    if (t < NBKT) binbase[t] = s[t] - v;
    if (t == 0) binbase[NBKT] = E;
}

// ---- hist[bin][blk] -> global scattered base offset (in place) ----
__global__ void scanK3(int* __restrict__ hist, const int* __restrict__ binbase,
                       int NBKT, int NB) {
    int bin = blockIdx.x * 256 + threadIdx.x;
    if (bin >= NBKT) return;
    int run = binbase[bin];
    for (int b = 0; b < NB; ++b) {
        int t = hist[bin * NB + b];
        hist[bin * NB + b] = run;
        run += t;
    }
}

// ---- bucketed scatter: tmp[] gets edges grouped by bucket, run-local writes
__global__ __launch_bounds__(256) void scatterH(const int* __restrict__ src,
                                                const int* __restrict__ dst,
                                                const int* __restrict__ hist,
                                                u64* __restrict__ tmp,
                                                int E, int NBKT, int NB) {
    __shared__ int offs[1024];
    int blk = blockIdx.x;
    for (int i = threadIdx.x; i < NBKT; i += 256) offs[i] = hist[i * NB + blk];
    __syncthreads();
    int beg = blk * CHUNK, end = min(E, beg + CHUNK);
    for (int e = beg + threadIdx.x; e < end; e += 256) {
        int d = dst[e];
        int pos = atomicAdd(&offs[d >> 7], 1);
        tmp[pos] = ((u64)(unsigned)d << 32) | (unsigned)src[e];
    }
}

// ---- per-bucket CSR compaction: rowptr + srcidx ----
__global__ __launch_bounds__(256) void bucket_csr(const u64* __restrict__ tmp,
                                                  const int* __restrict__ binbase,
                                                  int* __restrict__ rowptr,
                                                  int* __restrict__ srcidx,
                                                  int n) {
    __shared__ int cnt[128], sc[128], cnt2[128];
    int b = blockIdx.x;
    int bstart = binbase[b], bend = binbase[b + 1];
    if (threadIdx.x < 128) cnt[threadIdx.x] = 0;
    __syncthreads();
    for (int e = bstart + threadIdx.x; e < bend; e += 256) {
        int d = (int)(tmp[e] >> 32);
        atomicAdd(&cnt[d & 127], 1);
    }
    __syncthreads();
    if (threadIdx.x < 128) sc[threadIdx.x] = cnt[threadIdx.x];
    __syncthreads();
    for (int off = 1; off < 128; off <<= 1) {
        int u = 0;
        if (threadIdx.x < 128 && threadIdx.x >= off) u = sc[threadIdx.x - off];
        __syncthreads();
        if (threadIdx.x < 128) sc[threadIdx.x] += u;
        __syncthreads();
    }
    if (threadIdx.x < 128) {
        int excl = sc[threadIdx.x] - cnt[threadIdx.x];   // exclusive scan
        cnt2[threadIdx.x] = excl;
        int id = b * 128 + threadIdx.x;
        if (id <= n) rowptr[id] = bstart + excl;         // includes sentinel id==n
    }
    __syncthreads();
    for (int e = bstart + threadIdx.x; e < bend; e += 256) {
        u64 r = tmp[e];
        int d = (int)(r >> 32);
        int pos = bstart + atomicAdd(&cnt2[d & 127], 1);
        srcidx[pos] = (int)(r & 0xffffffffu);
    }
}

__global__ void dinv_k(const int* __restrict__ rowptr, float* __restrict__ dinv, int n) {
    int i = blockIdx.x * blockDim.x + threadIdx.x;
    if (i < n) dinv[i] = rsqrtf((float)(rowptr[i + 1] - rowptr[i]) + 1.0f);
}

// ---- w3 = W2 @ Wo  [128], c3 = b2.Wo + bo ----
__global__ void make_w3(const float* __restrict__ W2, const float* __restrict__ b2,
                        const float* __restrict__ Wo, const float* __restrict__ bo,
                        float* __restrict__ w3, float* __restrict__ c3) {
    int j = threadIdx.x;  // 128
    float s = 0.f;
    for (int d = 0; d < 64; ++d) s += W2[j * 64 + d] * Wo[d];
    w3[j] = s;
    if (j == 0) {
        float c = 0.f;
        for (int d = 0; d < 64; ++d) c += b2[d] * Wo[d];
        *c3 = c + bo[0];
    }
}

// ---- fp32 GEMM  C[n,128] = dinv[row] * (A[n,128] @ W[128,128]) ----
#define BK 32
#define LDP 132
__global__ __launch_bounds__(256, 4) void gemm_rt(const float* __restrict__ A,
                                                  const float* __restrict__ W,
                                                  const float* __restrict__ dinv,
                                                  float* __restrict__ C, int n) {
    __shared__ float As[BK][LDP];
    __shared__ float Ws[BK][LDP];
    const int tid = threadIdx.x;
    const int tx = tid & 15;
    const int ty = tid >> 4;
    const int row0 = blockIdx.x * 128;

    float acc[8][8];
#pragma unroll
    for (int i = 0; i < 8; ++i)
#pragma unroll
        for (int j = 0; j < 8; ++j) acc[i][j] = 0.f;

    for (int kc = 0; kc < 128; kc += BK) {
#pragma unroll
        for (int i = 0; i < 4; ++i) {
            int idx = tid + 256 * i;
            int r = idx >> 3, q = idx & 7;
            int row = row0 + r;
            float4 v = (row < n) ? *(const float4*)(A + (size_t)row * 128 + kc + q * 4)
                                 : make_float4(0.f, 0.f, 0.f, 0.f);
            As[q * 4 + 0][r] = v.x;
            As[q * 4 + 1][r] = v.y;
            As[q * 4 + 2][r] = v.z;
            As[q * 4 + 3][r] = v.w;
        }
#pragma unroll
        for (int i = 0; i < 4; ++i) {
            int idx = tid + 256 * i;
            int k = idx >> 5, q = idx & 31;
            float4 v = *(const float4*)(W + (size_t)(kc + k) * 128 + q * 4);
            *(float4*)(&Ws[k][q * 4]) = v;
        }
        __syncthreads();

#pragma unroll 8
        for (int k = 0; k < BK; ++k) {
            float a[8], w[8];
            *(float4*)&a[0] = *(const float4*)(&As[k][ty * 4]);
            *(float4*)&a[4] = *(const float4*)(&As[k][64 + ty * 4]);
            *(float4*)&w[0] = *(const float4*)(&Ws[k][tx * 4]);
            *(float4*)&w[4] = *(const float4*)(&Ws[k][64 + tx * 4]);
#pragma unroll
            for (int i = 0; i < 8; ++i)
#pragma unroll
                for (int j = 0; j < 8; ++j)
                    acc[i][j] = fmaf(a[i], w[j], acc[i][j]);
        }
        __syncthreads();
    }

#pragma unroll
    for (int i = 0; i < 8; ++i) {
        int row = row0 + ty * 4 + (i & 3) + ((i >= 4) ? 64 : 0);
        if (row < n) {
            float di = dinv[row];
            float4 o0, o1;
            o0.x = acc[i][0] * di; o0.y = acc[i][1] * di;
            o0.z = acc[i][2] * di; o0.w = acc[i][3] * di;
            o1.x = acc[i][4] * di; o1.y = acc[i][5] * di;
            o1.z = acc[i][6] * di; o1.w = acc[i][7] * di;
            *(float4*)(C + (size_t)row * 128 + tx * 4) = o0;
            *(float4*)(C + (size_t)row * 128 + 64 + tx * 4) = o1;
        }
    }
}

// ---- CSR gather aggregation: one wave per node, 2 edges in flight ----
__global__ __launch_bounds__(256) void agg_csr128(const int* __restrict__ rowptr,
                                                  const int* __restrict__ srcidx,
                                                  const float* __restrict__ dinv,
                                                  const float* __restrict__ G,
                                                  const float* __restrict__ b,
                                                  float* __restrict__ out,
                                                  int n, int do_relu) {
    int wid = (int)((blockIdx.x * (size_t)blockDim.x + threadIdx.x) >> 6);
    int lane = threadIdx.x & 63;
    if (wid >= n) return;
    int half = lane >> 5;
    int l = lane & 31;

    int beg = rowptr[wid], end = rowptr[wid + 1];
    float4 acc = make_float4(0.f, 0.f, 0.f, 0.f);
    if (half == 0)
        acc = *(const float4*)(G + (size_t)wid * 128 + l * 4);

    int e = beg + half;
    for (; e + 6 < end; e += 8) {
        int s0 = srcidx[e], s1 = srcidx[e + 2], s2 = srcidx[e + 4], s3 = srcidx[e + 6];
        float4 v0 = *(const float4*)(G + (size_t)s0 * 128 + l * 4);
        float4 v1 = *(const float4*)(G + (size_t)s1 * 128 + l * 4);
        float4 v2 = *(const float4*)(G + (size_t)s2 * 128 + l * 4);
        float4 v3 = *(const float4*)(G + (size_t)s3 * 128 + l * 4);
        acc.x += v0.x + v1.x + v2.x + v3.x;
        acc.y += v0.y + v1.y + v2.y + v3.y;
        acc.z += v0.z + v1.z + v2.z + v3.z;
        acc.w += v0.w + v1.w + v2.w + v3.w;
    }
    for (; e < end; e += 2) {
        int s = srcidx[e];
        float4 v = *(const float4*)(G + (size_t)s * 128 + l * 4);
        acc.x += v.x; acc.y += v.y; acc.z += v.z; acc.w += v.w;
    }

    acc.x += __shfl_xor(acc.x, 32, 64);
    acc.y += __shfl_xor(acc.y, 32, 64);
    acc.z += __shfl_xor(acc.z, 32, 64);
    acc.w += __shfl_xor(acc.w, 32, 64);

    if (half == 0) {
        float di = dinv[wid];
        float4 bb = *(const float4*)(b + l * 4);
        float4 o;
        o.x = di * acc.x + bb.x;
        o.y = di * acc.y + bb.y;
        o.z = di * acc.z + bb.z;
        o.w = di * acc.w + bb.w;
        if (do_relu) {
            o.x = fmaxf(o.x, 0.f); o.y = fmaxf(o.y, 0.f);
            o.z = fmaxf(o.z, 0.f); o.w = fmaxf(o.w, 0.f);
        }
        *(float4*)(out + (size_t)wid * 128 + l * 4) = o;
    }
}

// ---- ys[i] = dinv[i] * dot(H[i,:], w3), one wave per row ----
__global__ __launch_bounds__(256) void dotw3(const float* __restrict__ H,
                                             const float* __restrict__ w3,
                                             const float* __restrict__ dinv,
                                             float* __restrict__ ys, int n) {
    int wid = (int)((blockIdx.x * (size_t)blockDim.x + threadIdx.x) >> 6);
    int lane = threadIdx.x & 63;
    if (wid >= n) return;
    float2 h = *(const float2*)(H + (size_t)wid * 128 + lane * 2);
    float2 w = *(const float2*)(w3 + lane * 2);
    float v = h.x * w.x + h.y * w.y;
#pragma unroll
    for (int off = 32; off > 0; off >>= 1) v += __shfl_down(v, off, 64);
    if (lane == 0) ys[wid] = v * dinv[wid];
}

// ---- scalar CSR gather for fused layer3+proj ----
__global__ void agg_csr_scalar(const int* __restrict__ rowptr, const int* __restrict__ srcidx,
                               const float* __restrict__ dinv, const float* __restrict__ ys,
                               const float* __restrict__ c3, float* __restrict__ out, int n) {
    int i = blockIdx.x * blockDim.x + threadIdx.x;
    if (i >= n) return;
    int beg = rowptr[i], end = rowptr[i + 1];
    float acc = ys[i];
    int e = beg;
    for (; e + 3 < end; e += 4) {
        acc += ys[srcidx[e]] + ys[srcidx[e + 1]] + ys[srcidx[e + 2]] + ys[srcidx[e + 3]];
    }
    for (; e < end; ++e) acc += ys[srcidx[e]];
    out[i] = dinv[i] * acc + c3[0];
}

static inline size_t align4(size_t x) { return (x + 3) & ~(size_t)3; }

extern "C" void kernel_launch(void* const* d_in, const int* in_sizes, int n_in,
                              void* d_out, int out_size, void* d_ws, size_t ws_size,
                              hipStream_t stream) {
    const float* x  = (const float*)d_in[0];
    const int* ei   = (const int*)d_in[1];
    const float* W1 = (const float*)d_in[2];
    const float* b1 = (const float*)d_in[3];
    const float* Wh = (const float*)d_in[4];
    const float* bh = (const float*)d_in[5];
    const float* W2 = (const float*)d_in[6];
    const float* b2 = (const float*)d_in[7];
    const float* Wo = (const float*)d_in[8];
    const float* bo = (const float*)d_in[9];
    float* out = (float*)d_out;

    const int n = in_sizes[0] / F_DIM;
    const int E = in_sizes[1] / 2;
    const int* src = ei;
    const int* dst = ei + E;

    const int NB = (E + CHUNK - 1) / CHUNK;     // scatter chunks
    const int NBKT = (n >> 7) + 1;              // buckets (<=1024 for n<=131071)

    // workspace layout (4B elements, sections 16B-aligned)
    size_t o = 0;
    int* rowptr = (int*)d_ws + o;        o = align4(o + n + 1);
    int* srcidx = (int*)d_ws + o;        o = align4(o + E);
    int* hist   = (int*)d_ws + o;        o = align4(o + (size_t)NBKT * NB);
    int* binsum = (int*)d_ws + o;        o = align4(o + NBKT);
    int* binbase= (int*)d_ws + o;        o = align4(o + NBKT + 1);
    float* dinv = (float*)d_ws + o;      o = align4(o + n);
    float* w3   = (float*)d_ws + o;      o = align4(o + 128);
    float* c3   = (float*)d_ws + o;      o = align4(o + 4);
    float* bufA = (float*)d_ws + o;      o = align4(o + (size_t)n * 128);
    float* bufB = (float*)d_ws + o;      o = align4(o + (size_t)n * 128);
    u64* tmp = (u64*)bufA;               // aliases bufA (consumed before gemm1)

    const int B = (n + 255) / 256;

    // CSR build: bucket sort + per-bucket compaction
    histH<<<NB, 256, 0, stream>>>(dst, hist, E, NBKT, NB);
    scanK1<<<(NBKT + 255) / 256, 256, 0, stream>>>(hist, binsum, NBKT, NB);
    scanK2<<<1, 1024, 0, stream>>>(binsum, binbase, NBKT, E);
    scanK3<<<(NBKT + 255) / 256, 256, 0, stream>>>(hist, binbase, NBKT, NB);
    scatterH<<<NB, 256, 0, stream>>>(src, dst, hist, tmp, E, NBKT, NB);
    bucket_csr<<<NBKT, 256, 0, stream>>>(tmp, binbase, rowptr, srcidx, n);
    dinv_k<<<B, 256, 0, stream>>>(rowptr, dinv, n);
    make_w3<<<1, 128, 0, stream>>>(W2, b2, Wo, bo, w3, c3);

    const int GB = (n + 127) / 128;

    // layer 1
    gemm_rt<<<GB, 256, 0, stream>>>(x, W1, dinv, bufA, n);
    agg_csr128<<<(int)(((size_t)n * 64 + 255) / 256), 256, 0, stream>>>(
        rowptr, srcidx, dinv, bufA, b1, bufB, n, 1);

    // layer 2
    gemm_rt<<<GB, 256, 0, stream>>>(bufB, Wh, dinv, bufA, n);
    agg_csr128<<<(int)(((size_t)n * 64 + 255) / 256), 256, 0, stream>>>(
        rowptr, srcidx, dinv, bufA, bh, bufB, n, 1);

    // layer 3 + output projection
    dotw3<<<(int)(((size_t)n * 64 + 255) / 256), 256, 0, stream>>>(bufB, w3, dinv, bufA, n);
    agg_csr_scalar<<<B, 256, 0, stream>>>(rowptr, srcidx, dinv, bufA, c3, out, n);
}